// Round 8
// baseline (256.924 us; speedup 1.0000x reference)
//
#include <hip/hip_runtime.h>
#include <hip/hip_bf16.h>
#include <stdint.h>

// MHA fwd, B=4 T=2048 D=768 H=12 HD=64, fp32 io, NO mask, scale=1/8.
// R8: split-K attention: wave=64q (R4 frag math), block=256q, grid 48x8x2=768
// (3 blocks/CU, 12 waves/CU). Blocks write unnormalized bf16 O-partials +
// fp32 row-sums; elementwise reduce combines. Workspace overlaid (no growth):
//   OP0 -> Xb region (dead after qkv), OP1 -> Cb region, Lpart -> Wqkvt region,
//   reduce writes Ctx in-place into OP0 region; out_gemm reads it there.

#define HH   12
#define TT   2048
#define DIN  768
#define DOUT 768
#define HD   64
#define BB   4
#define MTOT (BB*TT)      // 8192
#define NQKV (3*DOUT)     // 2304
#define QSCALE 0.1803368801111832f   // 0.125 * log2(e)

typedef float  float4v  __attribute__((ext_vector_type(4)));
typedef float  float16v __attribute__((ext_vector_type(16)));
typedef __bf16 bf16x8   __attribute__((ext_vector_type(8)));
typedef short  short8v  __attribute__((ext_vector_type(8)));

#define AS1 __attribute__((address_space(1)))
#define AS3 __attribute__((address_space(3)))

static __device__ __forceinline__ void gload_lds16(const void* g, void* l) {
    __builtin_amdgcn_global_load_lds((AS1 void*)g, (AS3 void*)l, 16, 0, 0);
}

static __device__ __forceinline__ short f2bf(float f) {
    __bf16 h = (__bf16)f;
    return __builtin_bit_cast(short, h);
}
static __device__ __forceinline__ float bf2f(short s) {
    return (float)__builtin_bit_cast(__bf16, s);
}

// ---- merged prep: bz<4 = weight transpose tiles; bz==4 = cast x -> bf16 ----
__global__ __launch_bounds__(256) void prep_kernel(const float* __restrict__ x,
                                                   const float* __restrict__ Wq,
                                                   const float* __restrict__ Wk,
                                                   const float* __restrict__ Wv,
                                                   const float* __restrict__ Wo,
                                                   short* __restrict__ Xb,
                                                   short* __restrict__ Wqkvt,
                                                   short* __restrict__ Wot) {
    __shared__ short tile[32 * 33];
    const int bx = blockIdx.x, by = blockIdx.y, bz = blockIdx.z;
    if (bz == 4) {
        const int n4 = MTOT * DIN / 4;
        const int base = (by * 24 + bx) * 256 + threadIdx.x;
        for (int i = base; i < n4; i += 24 * 24 * 256) {
            float4 v = ((const float4*)x)[i];
            short4 o;
            o.x = f2bf(v.x); o.y = f2bf(v.y); o.z = f2bf(v.z); o.w = f2bf(v.w);
            ((short4*)Xb)[i] = o;
        }
        return;
    }
    const float* W = (bz == 0) ? Wq : (bz == 1) ? Wk : (bz == 2) ? Wv : Wo;
    const int tx = threadIdx.x & 31, ty = threadIdx.x >> 5;
    for (int i = 0; i < 4; i++) {
        int k = by * 32 + ty + i * 8;
        tile[(ty + i * 8) * 33 + tx] = f2bf(W[(size_t)k * DOUT + bx * 32 + tx]);
    }
    __syncthreads();
    for (int i = 0; i < 4; i++) {
        int n = bx * 32 + ty + i * 8;
        int k = by * 32 + tx;
        short v = tile[tx * 33 + ty + i * 8];
        if (bz < 3) Wqkvt[(size_t)(bz * DOUT + n) * DIN + k] = v;
        else        Wot[(size_t)n * DOUT + k] = v;
    }
}

// ---- QKV GEMM: C[8192][2304] = Xb @ Wqkvt^T ; BK=64 ----
__global__ __launch_bounds__(256) void qkv_gemm_kernel(const short* __restrict__ Xb,
                                                       const short* __restrict__ Wt,
                                                       short* __restrict__ Qb,
                                                       short* __restrict__ Kb,
                                                       short* __restrict__ Vt) {
    __shared__ __align__(16) short lds[16384];
    short* ldsA = lds;
    short* ldsB = lds + 8192;
    const int t = threadIdx.x;
    const int w = t >> 6, lane = t & 63;
    const int quad = lane >> 4, l15 = lane & 15;
    const int m0 = blockIdx.x * 128, n0 = blockIdx.y * 128;
    const int wm = (w >> 1) * 64, wn = (w & 1) * 64;

    float4v acc[4][4];
    for (int i = 0; i < 4; i++)
        for (int j = 0; j < 4; j++)
            acc[i][j] = (float4v)0.0f;

    int sOff[4], sRow[4];
#pragma unroll
    for (int g = 0; g < 4; g++) {
        int slot = g * 256 + t;
        int row = slot >> 3, ch = slot & 7;
        sRow[g] = row;
        sOff[g] = ((ch ^ (row & 7)) * 8);
    }

    for (int k0 = 0; k0 < DIN; k0 += 64) {
#pragma unroll
        for (int g = 0; g < 4; g++)
            gload_lds16(Xb + (size_t)(m0 + sRow[g]) * DIN + k0 + sOff[g], &ldsA[(g * 256 + t) * 8]);
#pragma unroll
        for (int g = 0; g < 4; g++)
            gload_lds16(Wt + (size_t)(n0 + sRow[g]) * DIN + k0 + sOff[g], &ldsB[(g * 256 + t) * 8]);
        __syncthreads();
#pragma unroll
        for (int f = 0; f < 2; f++) {
            bf16x8 af[4], bfr[4];
            for (int i = 0; i < 4; i++) {
                int row = wm + i * 16 + l15;
                af[i] = *(const bf16x8*)&ldsA[row * 64 + (((f * 4 + quad) ^ (row & 7)) * 8)];
            }
            for (int j = 0; j < 4; j++) {
                int row = wn + j * 16 + l15;
                bfr[j] = *(const bf16x8*)&ldsB[row * 64 + (((f * 4 + quad) ^ (row & 7)) * 8)];
            }
            for (int i = 0; i < 4; i++)
                for (int j = 0; j < 4; j++)
                    acc[i][j] = __builtin_amdgcn_mfma_f32_16x16x32_bf16(af[i], bfr[j], acc[i][j], 0, 0, 0);
        }
        __syncthreads();
    }

    const int which = n0 / DOUT;
    if (which < 2) {
        short* ldsT = lds;   // 128 x 128 shorts = 32 KB
        const float sc = (which == 0) ? QSCALE : 1.0f;
        short* dst = (which == 0) ? Qb : Kb;
        const int n0sec = n0 - which * DOUT;
        for (int i = 0; i < 4; i++)
            for (int j = 0; j < 4; j++) {
                int col = wn + j * 16 + l15;
                int cx = col >> 3, co = col & 7;
                for (int r = 0; r < 4; r++) {
                    int row = wm + i * 16 + quad * 4 + r;
                    ldsT[row * 128 + ((cx ^ (row & 7)) * 8 + co)] = f2bf(acc[i][j][r] * sc);
                }
            }
        __syncthreads();
        for (int p = 0; p < 8; p++) {
            int row = p * 16 + (t >> 4);
            int cL = t & 15;
            short8v v = *(const short8v*)&ldsT[row * 128 + ((cL ^ (row & 7)) * 8)];
            int mg = m0 + row;
            int b2 = mg >> 11, tq = mg & 2047;
            int colg = n0sec + cL * 8;
            int hh = colg >> 6, d = colg & 63;
            *(short8v*)&dst[((size_t)((b2 * HH + hh) * TT + tq) << 6) + d] = v;
        }
    } else {
        short* ldsT = lds;
        const int n0r = n0 - 2 * DOUT;
        const int b = m0 >> 11, tq0 = m0 & 2047;
        for (int i = 0; i < 4; i++)
            for (int j = 0; j < 4; j++)
                for (int r = 0; r < 4; r++) {
                    int nl = wn + j * 16 + l15;
                    int ml = wm + i * 16 + quad * 4 + r;
                    int c = ml >> 3, o = ml & 7;
                    ldsT[nl * 128 + ((c ^ (nl & 7)) * 8 + o)] = f2bf(acc[i][j][r]);
                }
        __syncthreads();
        for (int p = 0; p < 8; p++) {
            int nrow = p * 16 + (t >> 4);
            int cc = t & 15;
            short8v v = *(const short8v*)&ldsT[nrow * 128 + ((cc ^ (nrow & 7)) * 8)];
            int colg = n0r + nrow;
            int hh = colg >> 6, d = colg & 63;
            *(short8v*)&Vt[(size_t)((b * HH + hh) * HD + d) * TT + tq0 + cc * 8] = v;
        }
    }
}

// ---- Flash attention R8: split-K, wave=64q, 32x32x16, P in regs ----
// grid (48 bh, 8 q-blocks of 256, 2 key-halves); block = 4 waves
__global__ __launch_bounds__(256, 3) void attn_kernel(const short* __restrict__ Qb,
                                                      const short* __restrict__ Kb,
                                                      const short* __restrict__ Vt,
                                                      short* __restrict__ OP0,
                                                      short* __restrict__ OP1,
                                                      float* __restrict__ Lpart) {
    __shared__ __align__(16) short ldsK[2][64 * 64];
    __shared__ __align__(16) short ldsV[2][64 * 64];
    const int t = threadIdx.x;
    const int w = t >> 6, lane = t & 63;
    const int half = lane >> 5, m = lane & 31;
    const int bh = blockIdx.x;
    const int b = bh / HH, h = bh - b * HH;
    const int q0 = blockIdx.y * 256 + w * 64;
    const int kz = blockIdx.z;

    const short* Qbase = Qb + (size_t)bh * TT * HD;
    const short* Kbase = Kb + (size_t)bh * TT * HD + (size_t)kz * 1024 * HD;
    const short* Vbase = Vt + (size_t)bh * HD * TT + (size_t)kz * 1024;

    bf16x8 qf[2][4];
#pragma unroll
    for (int tile = 0; tile < 2; tile++)
#pragma unroll
        for (int s = 0; s < 4; s++)
            qf[tile][s] = *(const bf16x8*)&Qbase[(q0 + tile * 32 + m) * HD + s * 16 + half * 8];

    int kOff[2], vOff[2];
    {
        int r5 = t >> 3;
        int pi = ((r5 >> 3) & 1) * 16 + ((r5 >> 2) & 1) * 8 + ((r5 >> 4) & 1) * 4 + (r5 & 3);
#pragma unroll
        for (int g = 0; g < 2; g++) {
            kOff[g] = (g * 32 + pi) * 64 + (((t & 7) ^ (r5 & 7)) * 8);
            int vrow = g * 32 + r5;
            vOff[g] = vrow * TT + (((t & 7) ^ (vrow & 7)) * 8);
        }
    }

    auto stage = [&](int buf, int u0) {
#pragma unroll
        for (int g = 0; g < 2; g++)
            gload_lds16(Kbase + (size_t)u0 * 64 + kOff[g], &ldsK[buf][(g * 256 + t) * 8]);
#pragma unroll
        for (int g = 0; g < 2; g++)
            gload_lds16(Vbase + (size_t)u0 + vOff[g], &ldsV[buf][(g * 256 + t) * 8]);
    };

    float16v accO[2][2];
    accO[0][0] = (float16v)0.0f; accO[0][1] = (float16v)0.0f;
    accO[1][0] = (float16v)0.0f; accO[1][1] = (float16v)0.0f;
    float lsum[2] = {0.0f, 0.0f};

    stage(0, 0);

    for (int it = 0; it < 16; ++it) {
        __syncthreads();
        const int buf = it & 1;
        if (it + 1 < 16) stage(buf ^ 1, (it + 1) * 64);
        const short* K_ = &ldsK[buf][0];
        const short* V_ = &ldsV[buf][0];

#pragma unroll
        for (int kt = 0; kt < 2; kt++) {
            float16v st[2];
            st[0] = (float16v)0.0f; st[1] = (float16v)0.0f;
#pragma unroll
            for (int s = 0; s < 4; s++) {
                bf16x8 ka = *(const bf16x8*)&K_[(kt * 32 + m) * 64 + (((s * 2 + half) ^ (m & 7)) * 8)];
                st[0] = __builtin_amdgcn_mfma_f32_32x32x16_bf16(ka, qf[0][s], st[0], 0, 0, 0);
                st[1] = __builtin_amdgcn_mfma_f32_32x32x16_bf16(ka, qf[1][s], st[1], 0, 0, 0);
            }
            bf16x8 ap[2][2];
#pragma unroll
            for (int tile = 0; tile < 2; tile++) {
                float pe[16];
#pragma unroll
                for (int i = 0; i < 16; i++) pe[i] = __builtin_amdgcn_exp2f(st[tile][i]);
                float s01 = 0.0f;
#pragma unroll
                for (int i = 0; i < 16; i++) s01 += pe[i];
                lsum[tile] += s01;
#pragma unroll
                for (int i = 0; i < 4; i++) {
                    ap[tile][0][i]     = (__bf16)pe[i];
                    ap[tile][0][4 + i] = (__bf16)pe[8 + i];
                    ap[tile][1][i]     = (__bf16)pe[4 + i];
                    ap[tile][1][4 + i] = (__bf16)pe[12 + i];
                }
            }
#pragma unroll
            for (int ks = 0; ks < 2; ks++)
#pragma unroll
                for (int dt = 0; dt < 2; dt++) {
                    int row = dt * 32 + m;
                    bf16x8 bv = *(const bf16x8*)&V_[row * 64 + (((kt * 4 + ks * 2 + half) ^ (row & 7)) * 8)];
                    accO[0][dt] = __builtin_amdgcn_mfma_f32_32x32x16_bf16(ap[0][ks], bv, accO[0][dt], 0, 0, 0);
                    accO[1][dt] = __builtin_amdgcn_mfma_f32_32x32x16_bf16(ap[1][ks], bv, accO[1][dt], 0, 0, 0);
                }
        }
    }

    short* OP = (kz == 0) ? OP0 : OP1;
#pragma unroll
    for (int tile = 0; tile < 2; tile++) {
        float lrow = lsum[tile] + __shfl_xor(lsum[tile], 32);
        if (half == 0)
            Lpart[((size_t)kz * 48 + bh) * TT + q0 + tile * 32 + m] = lrow;
#pragma unroll
        for (int s = 0; s < 4; s++)
#pragma unroll
            for (int i = 0; i < 4; i++) {
                int reg = s * 4 + i;
                int qrow = i + s * 8 + half * 4;
                int qg = q0 + tile * 32 + qrow;
                size_t base = (size_t)(b * TT + qg) * DOUT + h * HD + m;
                OP[base]      = f2bf(accO[tile][0][reg]);
                OP[base + 32] = f2bf(accO[tile][1][reg]);
            }
    }
}

// ---- reduce: Ctx = (OP0 + OP1) / (L0 + L1), in place into OP0 region ----
__global__ __launch_bounds__(256) void reduce_kernel(short* __restrict__ OP0,
                                                     const short* __restrict__ OP1,
                                                     const float* __restrict__ Lpart) {
    int i8 = blockIdx.x * 256 + threadIdx.x;       // 786432 total
    size_t i = (size_t)i8 * 8;
    int c = (int)(i % DOUT);
    int qf_ = (int)(i / DOUT);                     // b*2048 + q
    int b = qf_ >> 11, q = qf_ & 2047;
    int h = c >> 6;
    int bh = b * HH + h;
    float l0 = Lpart[(size_t)bh * TT + q];
    float l1 = Lpart[(size_t)(48 + bh) * TT + q];
    float linv = 1.0f / (l0 + l1);
    short8v a = *(const short8v*)&OP0[i];
    short8v bb = *(const short8v*)&OP1[i];
    short8v o;
#pragma unroll
    for (int j = 0; j < 8; j++)
        o[j] = f2bf((bf2f(a[j]) + bf2f(bb[j])) * linv);
    *(short8v*)&OP0[i] = o;
}

// ---- Out GEMM: 64x128 tiles, BK=64, grid 128x6 = 768 blocks ----
__global__ __launch_bounds__(256) void out_gemm_kernel(const short* __restrict__ Cb,
                                                       const short* __restrict__ Wot,
                                                       const float* __restrict__ bo,
                                                       float* __restrict__ out) {
    __shared__ __align__(16) short ldsA[64 * 64];
    __shared__ __align__(16) short ldsB[128 * 64];
    const int t = threadIdx.x;
    const int w = t >> 6, lane = t & 63;
    const int quad = lane >> 4, l15 = lane & 15;
    const int m0 = blockIdx.x * 64, n0 = blockIdx.y * 128;
    const int wn = w * 32;

    float4v acc[4][2];
    for (int i = 0; i < 4; i++)
        for (int j = 0; j < 2; j++)
            acc[i][j] = (float4v)0.0f;

    for (int k0 = 0; k0 < DOUT; k0 += 64) {
#pragma unroll
        for (int g = 0; g < 2; g++) {
            int slot = g * 256 + t;
            int row = slot >> 3, ch = slot & 7;
            gload_lds16(Cb + (size_t)(m0 + row) * DOUT + k0 + ((ch ^ (row & 7)) * 8),
                        &ldsA[slot * 8]);
        }
#pragma unroll
        for (int g = 0; g < 4; g++) {
            int slot = g * 256 + t;
            int row = slot >> 3, ch = slot & 7;
            gload_lds16(Wot + (size_t)(n0 + row) * DOUT + k0 + ((ch ^ (row & 7)) * 8),
                        &ldsB[slot * 8]);
        }
        __syncthreads();
#pragma unroll
        for (int f = 0; f < 2; f++) {
            bf16x8 af[4], bfr[2];
            for (int i = 0; i < 4; i++) {
                int row = i * 16 + l15;
                af[i] = *(const bf16x8*)&ldsA[row * 64 + (((f * 4 + quad) ^ (row & 7)) * 8)];
            }
            for (int j = 0; j < 2; j++) {
                int row = wn + j * 16 + l15;
                bfr[j] = *(const bf16x8*)&ldsB[row * 64 + (((f * 4 + quad) ^ (row & 7)) * 8)];
            }
            for (int i = 0; i < 4; i++)
                for (int j = 0; j < 2; j++)
                    acc[i][j] = __builtin_amdgcn_mfma_f32_16x16x32_bf16(af[i], bfr[j], acc[i][j], 0, 0, 0);
        }
        __syncthreads();
    }

    for (int i = 0; i < 4; i++) {
        int m = m0 + i * 16 + quad * 4;
        for (int j = 0; j < 2; j++) {
            int n = n0 + wn + j * 16 + l15;
            float bias = bo[n];
            for (int r = 0; r < 4; r++)
                out[(size_t)(m + r) * DOUT + n] = acc[i][j][r] + bias;
        }
    }
}

extern "C" void kernel_launch(void* const* d_in, const int* in_sizes, int n_in,
                              void* d_out, int out_size, void* d_ws, size_t ws_size,
                              hipStream_t stream) {
    const float* x  = (const float*)d_in[0];
    const float* Wq = (const float*)d_in[1];
    const float* Wk = (const float*)d_in[2];
    const float* Wv = (const float*)d_in[3];
    const float* Wo = (const float*)d_in[4];
    const float* bo = (const float*)d_in[5];
    float* out = (float*)d_out;

    char* ws = (char*)d_ws;
    short* Xb    = (short*)(ws + 0);          // 12582912  (later: OP0 / Ctx)
    short* Wqkvt = (short*)(ws + 12582912);   //  3538944  (later: Lpart 786KB)
    short* Wot   = (short*)(ws + 16121856);   //  1179648
    short* Qb    = (short*)(ws + 17301504);   // 12582912
    short* Kb    = (short*)(ws + 29884416);   // 12582912
    short* Vt    = (short*)(ws + 42467328);   // 12582912
    short* Cb    = (short*)(ws + 55050240);   // 12582912  (later: OP1) -> 67633152 B

    short* OP0   = Xb;
    short* OP1   = Cb;
    float* Lpart = (float*)Wqkvt;
    short* Ctx   = OP0;   // reduce writes in place

    prep_kernel<<<dim3(24, 24, 5), 256, 0, stream>>>(x, Wq, Wk, Wv, Wo, Xb, Wqkvt, Wot);
    qkv_gemm_kernel<<<dim3(MTOT / 128, NQKV / 128), 256, 0, stream>>>(Xb, Wqkvt, Qb, Kb, Vt);
    attn_kernel<<<dim3(BB * HH, TT / 256, 2), 256, 0, stream>>>(Qb, Kb, Vt, OP0, OP1, Lpart);
    reduce_kernel<<<MTOT * DOUT / 8 / 256, 256, 0, stream>>>(OP0, OP1, Lpart);
    out_gemm_kernel<<<dim3(MTOT / 64, DOUT / 128), 256, 0, stream>>>(Ctx, Wot, bo, out);
}

// Round 9
// 256.152 us; speedup vs baseline: 1.0030x; 1.0030x over previous
//
#include <hip/hip_runtime.h>
#include <hip/hip_bf16.h>
#include <stdint.h>

// MHA fwd, B=4 T=2048 D=768 H=12 HD=64, fp32 io, NO mask, scale=1/8.
// R9: split-K attention with HEAD-CONTIGUOUS partials OP[kz][bh][q][64]
// (128B-line granular stores -> no RMW amplification; R8's 161MB WRITE bug).
// Reduce combines into [b,q,D] Ctx (Qb region). No workspace growth.

#define HH   12
#define TT   2048
#define DIN  768
#define DOUT 768
#define HD   64
#define BB   4
#define MTOT (BB*TT)      // 8192
#define NQKV (3*DOUT)     // 2304
#define QSCALE 0.1803368801111832f   // 0.125 * log2(e)

typedef float  float4v  __attribute__((ext_vector_type(4)));
typedef float  float16v __attribute__((ext_vector_type(16)));
typedef __bf16 bf16x8   __attribute__((ext_vector_type(8)));
typedef short  short8v  __attribute__((ext_vector_type(8)));

#define AS1 __attribute__((address_space(1)))
#define AS3 __attribute__((address_space(3)))

static __device__ __forceinline__ void gload_lds16(const void* g, void* l) {
    __builtin_amdgcn_global_load_lds((AS1 void*)g, (AS3 void*)l, 16, 0, 0);
}

static __device__ __forceinline__ short f2bf(float f) {
    __bf16 h = (__bf16)f;
    return __builtin_bit_cast(short, h);
}
static __device__ __forceinline__ float bf2f(short s) {
    return (float)__builtin_bit_cast(__bf16, s);
}

// ---- merged prep: bz<4 = weight transpose tiles; bz==4 = cast x -> bf16 ----
__global__ __launch_bounds__(256) void prep_kernel(const float* __restrict__ x,
                                                   const float* __restrict__ Wq,
                                                   const float* __restrict__ Wk,
                                                   const float* __restrict__ Wv,
                                                   const float* __restrict__ Wo,
                                                   short* __restrict__ Xb,
                                                   short* __restrict__ Wqkvt,
                                                   short* __restrict__ Wot) {
    __shared__ short tile[32 * 33];
    const int bx = blockIdx.x, by = blockIdx.y, bz = blockIdx.z;
    if (bz == 4) {
        const int n4 = MTOT * DIN / 4;
        const int base = (by * 24 + bx) * 256 + threadIdx.x;
        for (int i = base; i < n4; i += 24 * 24 * 256) {
            float4 v = ((const float4*)x)[i];
            short4 o;
            o.x = f2bf(v.x); o.y = f2bf(v.y); o.z = f2bf(v.z); o.w = f2bf(v.w);
            ((short4*)Xb)[i] = o;
        }
        return;
    }
    const float* W = (bz == 0) ? Wq : (bz == 1) ? Wk : (bz == 2) ? Wv : Wo;
    const int tx = threadIdx.x & 31, ty = threadIdx.x >> 5;
    for (int i = 0; i < 4; i++) {
        int k = by * 32 + ty + i * 8;
        tile[(ty + i * 8) * 33 + tx] = f2bf(W[(size_t)k * DOUT + bx * 32 + tx]);
    }
    __syncthreads();
    for (int i = 0; i < 4; i++) {
        int n = bx * 32 + ty + i * 8;
        int k = by * 32 + tx;
        short v = tile[tx * 33 + ty + i * 8];
        if (bz < 3) Wqkvt[(size_t)(bz * DOUT + n) * DIN + k] = v;
        else        Wot[(size_t)n * DOUT + k] = v;
    }
}

// ---- QKV GEMM: C[8192][2304] = Xb @ Wqkvt^T ; BK=64 ----
__global__ __launch_bounds__(256) void qkv_gemm_kernel(const short* __restrict__ Xb,
                                                       const short* __restrict__ Wt,
                                                       short* __restrict__ Qb,
                                                       short* __restrict__ Kb,
                                                       short* __restrict__ Vt) {
    __shared__ __align__(16) short lds[16384];
    short* ldsA = lds;
    short* ldsB = lds + 8192;
    const int t = threadIdx.x;
    const int w = t >> 6, lane = t & 63;
    const int quad = lane >> 4, l15 = lane & 15;
    const int m0 = blockIdx.x * 128, n0 = blockIdx.y * 128;
    const int wm = (w >> 1) * 64, wn = (w & 1) * 64;

    float4v acc[4][4];
    for (int i = 0; i < 4; i++)
        for (int j = 0; j < 4; j++)
            acc[i][j] = (float4v)0.0f;

    int sOff[4], sRow[4];
#pragma unroll
    for (int g = 0; g < 4; g++) {
        int slot = g * 256 + t;
        int row = slot >> 3, ch = slot & 7;
        sRow[g] = row;
        sOff[g] = ((ch ^ (row & 7)) * 8);
    }

    for (int k0 = 0; k0 < DIN; k0 += 64) {
#pragma unroll
        for (int g = 0; g < 4; g++)
            gload_lds16(Xb + (size_t)(m0 + sRow[g]) * DIN + k0 + sOff[g], &ldsA[(g * 256 + t) * 8]);
#pragma unroll
        for (int g = 0; g < 4; g++)
            gload_lds16(Wt + (size_t)(n0 + sRow[g]) * DIN + k0 + sOff[g], &ldsB[(g * 256 + t) * 8]);
        __syncthreads();
#pragma unroll
        for (int f = 0; f < 2; f++) {
            bf16x8 af[4], bfr[4];
            for (int i = 0; i < 4; i++) {
                int row = wm + i * 16 + l15;
                af[i] = *(const bf16x8*)&ldsA[row * 64 + (((f * 4 + quad) ^ (row & 7)) * 8)];
            }
            for (int j = 0; j < 4; j++) {
                int row = wn + j * 16 + l15;
                bfr[j] = *(const bf16x8*)&ldsB[row * 64 + (((f * 4 + quad) ^ (row & 7)) * 8)];
            }
            for (int i = 0; i < 4; i++)
                for (int j = 0; j < 4; j++)
                    acc[i][j] = __builtin_amdgcn_mfma_f32_16x16x32_bf16(af[i], bfr[j], acc[i][j], 0, 0, 0);
        }
        __syncthreads();
    }

    const int which = n0 / DOUT;
    if (which < 2) {
        short* ldsT = lds;   // 128 x 128 shorts = 32 KB
        const float sc = (which == 0) ? QSCALE : 1.0f;
        short* dst = (which == 0) ? Qb : Kb;
        const int n0sec = n0 - which * DOUT;
        for (int i = 0; i < 4; i++)
            for (int j = 0; j < 4; j++) {
                int col = wn + j * 16 + l15;
                int cx = col >> 3, co = col & 7;
                for (int r = 0; r < 4; r++) {
                    int row = wm + i * 16 + quad * 4 + r;
                    ldsT[row * 128 + ((cx ^ (row & 7)) * 8 + co)] = f2bf(acc[i][j][r] * sc);
                }
            }
        __syncthreads();
        for (int p = 0; p < 8; p++) {
            int row = p * 16 + (t >> 4);
            int cL = t & 15;
            short8v v = *(const short8v*)&ldsT[row * 128 + ((cL ^ (row & 7)) * 8)];
            int mg = m0 + row;
            int b2 = mg >> 11, tq = mg & 2047;
            int colg = n0sec + cL * 8;
            int hh = colg >> 6, d = colg & 63;
            *(short8v*)&dst[((size_t)((b2 * HH + hh) * TT + tq) << 6) + d] = v;
        }
    } else {
        short* ldsT = lds;
        const int n0r = n0 - 2 * DOUT;
        const int b = m0 >> 11, tq0 = m0 & 2047;
        for (int i = 0; i < 4; i++)
            for (int j = 0; j < 4; j++)
                for (int r = 0; r < 4; r++) {
                    int nl = wn + j * 16 + l15;
                    int ml = wm + i * 16 + quad * 4 + r;
                    int c = ml >> 3, o = ml & 7;
                    ldsT[nl * 128 + ((c ^ (nl & 7)) * 8 + o)] = f2bf(acc[i][j][r]);
                }
        __syncthreads();
        for (int p = 0; p < 8; p++) {
            int nrow = p * 16 + (t >> 4);
            int cc = t & 15;
            short8v v = *(const short8v*)&ldsT[nrow * 128 + ((cc ^ (nrow & 7)) * 8)];
            int colg = n0r + nrow;
            int hh = colg >> 6, d = colg & 63;
            *(short8v*)&Vt[(size_t)((b * HH + hh) * HD + d) * TT + tq0 + cc * 8] = v;
        }
    }
}

// ---- Flash attention R9: split-K, wave=64q, head-contiguous partials ----
// grid (48 bh, 8 q-blocks of 256, 2 key-halves); block = 4 waves
__global__ __launch_bounds__(256, 3) void attn_kernel(const short* __restrict__ Qb,
                                                      const short* __restrict__ Kb,
                                                      const short* __restrict__ Vt,
                                                      short* __restrict__ OPa,
                                                      short* __restrict__ OPb,
                                                      float* __restrict__ Lpart) {
    __shared__ __align__(16) short ldsK[2][64 * 64];
    __shared__ __align__(16) short ldsV[2][64 * 64];
    const int t = threadIdx.x;
    const int w = t >> 6, lane = t & 63;
    const int half = lane >> 5, m = lane & 31;
    const int bh = blockIdx.x;
    const int q0 = blockIdx.y * 256 + w * 64;
    const int kz = blockIdx.z;

    const short* Qbase = Qb + (size_t)bh * TT * HD;
    const short* Kbase = Kb + (size_t)bh * TT * HD + (size_t)kz * 1024 * HD;
    const short* Vbase = Vt + (size_t)bh * HD * TT + (size_t)kz * 1024;

    bf16x8 qf[2][4];
#pragma unroll
    for (int tile = 0; tile < 2; tile++)
#pragma unroll
        for (int s = 0; s < 4; s++)
            qf[tile][s] = *(const bf16x8*)&Qbase[(q0 + tile * 32 + m) * HD + s * 16 + half * 8];

    int kOff[2], vOff[2];
    {
        int r5 = t >> 3;
        int pi = ((r5 >> 3) & 1) * 16 + ((r5 >> 2) & 1) * 8 + ((r5 >> 4) & 1) * 4 + (r5 & 3);
#pragma unroll
        for (int g = 0; g < 2; g++) {
            kOff[g] = (g * 32 + pi) * 64 + (((t & 7) ^ (r5 & 7)) * 8);
            int vrow = g * 32 + r5;
            vOff[g] = vrow * TT + (((t & 7) ^ (vrow & 7)) * 8);
        }
    }

    auto stage = [&](int buf, int u0) {
#pragma unroll
        for (int g = 0; g < 2; g++)
            gload_lds16(Kbase + (size_t)u0 * 64 + kOff[g], &ldsK[buf][(g * 256 + t) * 8]);
#pragma unroll
        for (int g = 0; g < 2; g++)
            gload_lds16(Vbase + (size_t)u0 + vOff[g], &ldsV[buf][(g * 256 + t) * 8]);
    };

    float16v accO[2][2];
    accO[0][0] = (float16v)0.0f; accO[0][1] = (float16v)0.0f;
    accO[1][0] = (float16v)0.0f; accO[1][1] = (float16v)0.0f;
    float lsum[2] = {0.0f, 0.0f};

    stage(0, 0);

    for (int it = 0; it < 16; ++it) {
        __syncthreads();
        const int buf = it & 1;
        if (it + 1 < 16) stage(buf ^ 1, (it + 1) * 64);
        const short* K_ = &ldsK[buf][0];
        const short* V_ = &ldsV[buf][0];

#pragma unroll
        for (int kt = 0; kt < 2; kt++) {
            float16v st[2];
            st[0] = (float16v)0.0f; st[1] = (float16v)0.0f;
#pragma unroll
            for (int s = 0; s < 4; s++) {
                bf16x8 ka = *(const bf16x8*)&K_[(kt * 32 + m) * 64 + (((s * 2 + half) ^ (m & 7)) * 8)];
                st[0] = __builtin_amdgcn_mfma_f32_32x32x16_bf16(ka, qf[0][s], st[0], 0, 0, 0);
                st[1] = __builtin_amdgcn_mfma_f32_32x32x16_bf16(ka, qf[1][s], st[1], 0, 0, 0);
            }
            bf16x8 ap[2][2];
#pragma unroll
            for (int tile = 0; tile < 2; tile++) {
                float pe[16];
#pragma unroll
                for (int i = 0; i < 16; i++) pe[i] = __builtin_amdgcn_exp2f(st[tile][i]);
                float s01 = 0.0f;
#pragma unroll
                for (int i = 0; i < 16; i++) s01 += pe[i];
                lsum[tile] += s01;
#pragma unroll
                for (int i = 0; i < 4; i++) {
                    ap[tile][0][i]     = (__bf16)pe[i];
                    ap[tile][0][4 + i] = (__bf16)pe[8 + i];
                    ap[tile][1][i]     = (__bf16)pe[4 + i];
                    ap[tile][1][4 + i] = (__bf16)pe[12 + i];
                }
            }
#pragma unroll
            for (int ks = 0; ks < 2; ks++)
#pragma unroll
                for (int dt = 0; dt < 2; dt++) {
                    int row = dt * 32 + m;
                    bf16x8 bv = *(const bf16x8*)&V_[row * 64 + (((kt * 4 + ks * 2 + half) ^ (row & 7)) * 8)];
                    accO[0][dt] = __builtin_amdgcn_mfma_f32_32x32x16_bf16(ap[0][ks], bv, accO[0][dt], 0, 0, 0);
                    accO[1][dt] = __builtin_amdgcn_mfma_f32_32x32x16_bf16(ap[1][ks], bv, accO[1][dt], 0, 0, 0);
                }
        }
    }

    // head-contiguous partial store: OP[(bh*TT + q)*64 + d] -> 128B lines
    short* OP = (kz == 0) ? OPa : OPb;
#pragma unroll
    for (int tile = 0; tile < 2; tile++) {
        float lrow = lsum[tile] + __shfl_xor(lsum[tile], 32);
        if (half == 0)
            Lpart[((size_t)kz * 48 + bh) * TT + q0 + tile * 32 + m] = lrow;
#pragma unroll
        for (int s = 0; s < 4; s++)
#pragma unroll
            for (int i = 0; i < 4; i++) {
                int reg = s * 4 + i;
                int qrow = i + s * 8 + half * 4;
                int qg = q0 + tile * 32 + qrow;
                size_t base = ((size_t)bh * TT + qg) * 64 + m;
                OP[base]      = f2bf(accO[tile][0][reg]);
                OP[base + 32] = f2bf(accO[tile][1][reg]);
            }
    }
}

// ---- reduce: Ctx[b,q,D] = (OPa + OPb) / (L0 + L1) ----
__global__ __launch_bounds__(256) void reduce_kernel(const short* __restrict__ OPa,
                                                     const short* __restrict__ OPb,
                                                     const float* __restrict__ Lpart,
                                                     short* __restrict__ Ctx) {
    int i8 = blockIdx.x * 256 + threadIdx.x;   // 786432 total
    size_t i = (size_t)i8 * 8;
    int d8 = i8 & 7;
    int qbh = i8 >> 3;                          // bh*TT + q
    int q = qbh & (TT - 1);
    int bh = qbh >> 11;
    int b = bh / HH, h = bh - b * HH;
    float l0 = Lpart[(size_t)qbh];
    float l1 = Lpart[(size_t)48 * TT + qbh];
    float linv = 1.0f / (l0 + l1);
    short8v a = *(const short8v*)&OPa[i];
    short8v c = *(const short8v*)&OPb[i];
    short8v o;
#pragma unroll
    for (int j = 0; j < 8; j++)
        o[j] = f2bf((bf2f(a[j]) + bf2f(c[j])) * linv);
    *(short8v*)&Ctx[(size_t)(b * TT + q) * DOUT + h * HD + d8 * 8] = o;
}

// ---- Out GEMM: 64x128 tiles, BK=64, grid 128x6 = 768 blocks ----
__global__ __launch_bounds__(256) void out_gemm_kernel(const short* __restrict__ Cb,
                                                       const short* __restrict__ Wot,
                                                       const float* __restrict__ bo,
                                                       float* __restrict__ out) {
    __shared__ __align__(16) short ldsA[64 * 64];
    __shared__ __align__(16) short ldsB[128 * 64];
    const int t = threadIdx.x;
    const int w = t >> 6, lane = t & 63;
    const int quad = lane >> 4, l15 = lane & 15;
    const int m0 = blockIdx.x * 64, n0 = blockIdx.y * 128;
    const int wn = w * 32;

    float4v acc[4][2];
    for (int i = 0; i < 4; i++)
        for (int j = 0; j < 2; j++)
            acc[i][j] = (float4v)0.0f;

    for (int k0 = 0; k0 < DOUT; k0 += 64) {
#pragma unroll
        for (int g = 0; g < 2; g++) {
            int slot = g * 256 + t;
            int row = slot >> 3, ch = slot & 7;
            gload_lds16(Cb + (size_t)(m0 + row) * DOUT + k0 + ((ch ^ (row & 7)) * 8),
                        &ldsA[slot * 8]);
        }
#pragma unroll
        for (int g = 0; g < 4; g++) {
            int slot = g * 256 + t;
            int row = slot >> 3, ch = slot & 7;
            gload_lds16(Wot + (size_t)(n0 + row) * DOUT + k0 + ((ch ^ (row & 7)) * 8),
                        &ldsB[slot * 8]);
        }
        __syncthreads();
#pragma unroll
        for (int f = 0; f < 2; f++) {
            bf16x8 af[4], bfr[2];
            for (int i = 0; i < 4; i++) {
                int row = i * 16 + l15;
                af[i] = *(const bf16x8*)&ldsA[row * 64 + (((f * 4 + quad) ^ (row & 7)) * 8)];
            }
            for (int j = 0; j < 2; j++) {
                int row = wn + j * 16 + l15;
                bfr[j] = *(const bf16x8*)&ldsB[row * 64 + (((f * 4 + quad) ^ (row & 7)) * 8)];
            }
            for (int i = 0; i < 4; i++)
                for (int j = 0; j < 2; j++)
                    acc[i][j] = __builtin_amdgcn_mfma_f32_16x16x32_bf16(af[i], bfr[j], acc[i][j], 0, 0, 0);
        }
        __syncthreads();
    }

    for (int i = 0; i < 4; i++) {
        int m = m0 + i * 16 + quad * 4;
        for (int j = 0; j < 2; j++) {
            int n = n0 + wn + j * 16 + l15;
            float bias = bo[n];
            for (int r = 0; r < 4; r++)
                out[(size_t)(m + r) * DOUT + n] = acc[i][j][r] + bias;
        }
    }
}

extern "C" void kernel_launch(void* const* d_in, const int* in_sizes, int n_in,
                              void* d_out, int out_size, void* d_ws, size_t ws_size,
                              hipStream_t stream) {
    const float* x  = (const float*)d_in[0];
    const float* Wq = (const float*)d_in[1];
    const float* Wk = (const float*)d_in[2];
    const float* Wv = (const float*)d_in[3];
    const float* Wo = (const float*)d_in[4];
    const float* bo = (const float*)d_in[5];
    float* out = (float*)d_out;

    char* ws = (char*)d_ws;
    short* Xb    = (short*)(ws + 0);          // 12582912  (later: OPa)
    short* Wqkvt = (short*)(ws + 12582912);   //  3538944  (later: Lpart 786KB)
    short* Wot   = (short*)(ws + 16121856);   //  1179648
    short* Qb    = (short*)(ws + 17301504);   // 12582912  (later: Ctx)
    short* Kb    = (short*)(ws + 29884416);   // 12582912
    short* Vt    = (short*)(ws + 42467328);   // 12582912
    short* Cb    = (short*)(ws + 55050240);   // 12582912  (later: OPb) -> 67633152 B

    short* OPa   = Xb;
    short* OPb   = Cb;
    float* Lpart = (float*)Wqkvt;
    short* Ctx   = Qb;   // dead after attn; reduce writes [b,q,D] here

    prep_kernel<<<dim3(24, 24, 5), 256, 0, stream>>>(x, Wq, Wk, Wv, Wo, Xb, Wqkvt, Wot);
    qkv_gemm_kernel<<<dim3(MTOT / 128, NQKV / 128), 256, 0, stream>>>(Xb, Wqkvt, Qb, Kb, Vt);
    attn_kernel<<<dim3(BB * HH, TT / 256, 2), 256, 0, stream>>>(Qb, Kb, Vt, OPa, OPb, Lpart);
    reduce_kernel<<<MTOT * DOUT / 8 / 256, 256, 0, stream>>>(OPa, OPb, Lpart, Ctx);
    out_gemm_kernel<<<dim3(MTOT / 64, DOUT / 128), 256, 0, stream>>>(Ctx, Wot, bo, out);
}